// Round 1
// baseline (399.353 us; speedup 1.0000x reference)
//
#include <hip/hip_runtime.h>
#include <math.h>

// Problem constants (from reference setup_inputs)
constexpr int B = 1024;
constexpr int D = 128;
constexpr int Q = 65536;
#define TEMP_INV 5.0f   // 1 / 0.2
#define EPS 1e-12f

__device__ __forceinline__ float wave_reduce_sum(float v) {
    #pragma unroll
    for (int off = 32; off > 0; off >>= 1) v += __shfl_xor(v, off);
    return v;
}

// --- K1: normalize g1,g2 rows; write q to ws; pos_sim to out and ws -------
// grid = B blocks, 128 threads (one thread per feature dim)
__global__ void k_norm_pos(const float* __restrict__ g1,
                           const float* __restrict__ g2,
                           float* __restrict__ qn,
                           float* __restrict__ out_pos,
                           float* __restrict__ ws_pos) {
    int b = blockIdx.x;
    int t = threadIdx.x;           // 0..127
    int w = t >> 6, lane = t & 63;
    float x = g1[b * D + t];
    float y = g2[b * D + t];
    __shared__ float sx[2], sy[2], sp[2];
    float xs = wave_reduce_sum(x * x);
    float ys = wave_reduce_sum(y * y);
    if (lane == 0) { sx[w] = xs; sy[w] = ys; }
    __syncthreads();
    float ix = 1.0f / fmaxf(sqrtf(sx[0] + sx[1]), EPS);
    float iy = 1.0f / fmaxf(sqrtf(sy[0] + sy[1]), EPS);
    float qv = x * ix;
    float kv = y * iy;
    qn[b * D + t] = qv;
    float p = wave_reduce_sum(qv * kv);
    if (lane == 0) sp[w] = p;
    __syncthreads();
    if (t == 0) {
        float pos = (sp[0] + sp[1]) * TEMP_INV;
        out_pos[b] = pos;   // pos_sim output region
        ws_pos[b]  = pos;   // reused by loss kernel
    }
}

// --- K2: inverse L2 norms of queue rows -----------------------------------
// one wave per row; 4 rows per 256-thread block
__global__ void k_qinv(const float* __restrict__ queue, float* __restrict__ qinv) {
    int wv = threadIdx.x >> 6;
    int lane = threadIdx.x & 63;
    int row = blockIdx.x * 4 + wv;
    const float2* p = (const float2*)(queue + (size_t)row * D);
    float2 v = p[lane];
    float s = wave_reduce_sum(v.x * v.x + v.y * v.y);
    if (lane == 0) qinv[row] = 1.0f / fmaxf(sqrtf(s), EPS);
}

// --- K3: neg_sim GEMM: C[b][j] = dot(q[b], queue[j]) * qinv[j] * 5 --------
// 64x64 tile per 256-thread block, 4x4 micro-tile per thread, K chunks of 32
__global__ __launch_bounds__(256) void k_gemm(const float* __restrict__ qn,
                                              const float* __restrict__ queue,
                                              const float* __restrict__ qinv,
                                              float* __restrict__ neg) {
    __shared__ float As[64][33];
    __shared__ float Bs[64][33];
    const int tx = threadIdx.x & 15;
    const int ty = threadIdx.x >> 4;
    const int colBase = blockIdx.x * 64;   // over Q
    const int rowBase = blockIdx.y * 64;   // over B

    float acc[4][4] = {};

    for (int kk = 0; kk < D; kk += 32) {
        const int t = threadIdx.x;
        #pragma unroll
        for (int it = 0; it < 2; ++it) {
            int r  = (t >> 3) + it * 32;
            int c4 = (t & 7) * 4;
            float4 va = *(const float4*)(qn    + (size_t)(rowBase + r) * D + kk + c4);
            float4 vb = *(const float4*)(queue + (size_t)(colBase + r) * D + kk + c4);
            As[r][c4 + 0] = va.x; As[r][c4 + 1] = va.y;
            As[r][c4 + 2] = va.z; As[r][c4 + 3] = va.w;
            Bs[r][c4 + 0] = vb.x; Bs[r][c4 + 1] = vb.y;
            Bs[r][c4 + 2] = vb.z; Bs[r][c4 + 3] = vb.w;
        }
        __syncthreads();
        #pragma unroll
        for (int k = 0; k < 32; ++k) {
            float a[4], bb[4];
            #pragma unroll
            for (int i = 0; i < 4; ++i) a[i]  = As[ty * 4 + i][k];
            #pragma unroll
            for (int j = 0; j < 4; ++j) bb[j] = Bs[tx * 4 + j][k];
            #pragma unroll
            for (int i = 0; i < 4; ++i)
                #pragma unroll
                for (int j = 0; j < 4; ++j)
                    acc[i][j] += a[i] * bb[j];
        }
        __syncthreads();
    }

    // epilogue: scale by qinv[col] / T, vectorized float4 stores
    #pragma unroll
    for (int i = 0; i < 4; ++i) {
        int row = rowBase + ty * 4 + i;
        int col = colBase + tx * 4;
        float4 o;
        o.x = acc[i][0] * qinv[col + 0] * TEMP_INV;
        o.y = acc[i][1] * qinv[col + 1] * TEMP_INV;
        o.z = acc[i][2] * qinv[col + 2] * TEMP_INV;
        o.w = acc[i][3] * qinv[col + 3] * TEMP_INV;
        *(float4*)(neg + (size_t)row * Q + col) = o;
    }
}

// --- K4: per-row online logsumexp over neg row + pos; loss_b --------------
__global__ __launch_bounds__(256) void k_row_lse(const float* __restrict__ neg,
                                                 const float* __restrict__ ws_pos,
                                                 float* __restrict__ loss_b) {
    int b = blockIdx.x;
    const float4* row = (const float4*)(neg + (size_t)b * Q);
    float m = -3.4e38f, s = 0.0f;
    for (int i = threadIdx.x; i < Q / 4; i += 256) {
        float4 v = row[i];
        float mv = fmaxf(fmaxf(v.x, v.y), fmaxf(v.z, v.w));
        if (mv > m) { s *= __expf(m - mv); m = mv; }
        s += __expf(v.x - m) + __expf(v.y - m) + __expf(v.z - m) + __expf(v.w - m);
    }
    // merge (m,s) across wave
    #pragma unroll
    for (int off = 32; off > 0; off >>= 1) {
        float m2 = __shfl_xor(m, off);
        float s2 = __shfl_xor(s, off);
        float M = fmaxf(m, m2);
        s = s * __expf(m - M) + s2 * __expf(m2 - M);
        m = M;
    }
    __shared__ float sm[4], ss[4];
    int w = threadIdx.x >> 6, lane = threadIdx.x & 63;
    if (lane == 0) { sm[w] = m; ss[w] = s; }
    __syncthreads();
    if (threadIdx.x == 0) {
        m = sm[0]; s = ss[0];
        #pragma unroll
        for (int i = 1; i < 4; ++i) {
            float M = fmaxf(m, sm[i]);
            s = s * __expf(m - M) + ss[i] * __expf(sm[i] - M);
            m = M;
        }
        float p = ws_pos[b];
        float M = fmaxf(m, p);
        s = s * __expf(m - M) + __expf(p - M);
        float lse = M + logf(s);
        loss_b[b] = lse - p;   // -log_softmax[:,0]
    }
}

// --- K5: mean of loss_b -> out[0] -----------------------------------------
__global__ void k_loss_mean(const float* __restrict__ loss_b, float* __restrict__ out) {
    float s = 0.0f;
    for (int i = threadIdx.x; i < B; i += 256) s += loss_b[i];
    s = wave_reduce_sum(s);
    __shared__ float sw[4];
    int w = threadIdx.x >> 6, lane = threadIdx.x & 63;
    if (lane == 0) sw[w] = s;
    __syncthreads();
    if (threadIdx.x == 0) out[0] = (sw[0] + sw[1] + sw[2] + sw[3]) / (float)B;
}

extern "C" void kernel_launch(void* const* d_in, const int* in_sizes, int n_in,
                              void* d_out, int out_size, void* d_ws, size_t ws_size,
                              hipStream_t stream) {
    const float* g1    = (const float*)d_in[0];
    const float* g2    = (const float*)d_in[1];
    const float* queue = (const float*)d_in[2];
    float* out = (float*)d_out;

    float* out_pos = out + 1;          // pos_sim [B]
    float* neg     = out + 1 + B;      // neg_sim [B][Q]

    // workspace layout (floats): qn[B*D] | qinv[Q] | ws_pos[B] | loss_b[B]
    float* ws     = (float*)d_ws;
    float* qn     = ws;
    float* qinv   = qn + (size_t)B * D;
    float* ws_pos = qinv + Q;
    float* loss_b = ws_pos + B;

    k_norm_pos<<<B, 128, 0, stream>>>(g1, g2, qn, out_pos, ws_pos);
    k_qinv<<<Q / 4, 256, 0, stream>>>(queue, qinv);
    dim3 g3(Q / 64, B / 64);
    k_gemm<<<g3, 256, 0, stream>>>(qn, queue, qinv, neg);
    k_row_lse<<<B, 256, 0, stream>>>(neg, ws_pos, loss_b);
    k_loss_mean<<<1, 256, 0, stream>>>(loss_b, out);
}

// Round 2
// 121.036 us; speedup vs baseline: 3.2995x; 3.2995x over previous
//
#include <hip/hip_runtime.h>
#include <math.h>

constexpr int B = 1024;
constexpr int D = 128;
constexpr int Q = 65536;
constexpr int NPART = 1024;      // partial-LSE slots per row (512 col-blocks x 2 waves)
#define TEMP_INV 5.0f
#define EPS 1e-12f

typedef __bf16 bf16x8 __attribute__((ext_vector_type(8)));
typedef float  f32x4  __attribute__((ext_vector_type(4)));

__device__ __forceinline__ float wave_reduce_sum(float v) {
    #pragma unroll
    for (int off = 32; off > 0; off >>= 1) v += __shfl_xor(v, off);
    return v;
}

__device__ __forceinline__ unsigned short f2bf(float x) {
    unsigned int u = __float_as_uint(x);
    unsigned int r = (u + 0x7FFFu + ((u >> 16) & 1u)) >> 16;   // RNE
    return (unsigned short)r;
}

// --- K1: normalize g1,g2 rows; qn (bf16) to ws; pos_sim to out and ws ------
__global__ void k_norm_pos(const float* __restrict__ g1,
                           const float* __restrict__ g2,
                           unsigned short* __restrict__ qnb,
                           float* __restrict__ out_pos,
                           float* __restrict__ ws_pos) {
    int b = blockIdx.x;
    int t = threadIdx.x;           // 0..127
    int w = t >> 6, lane = t & 63;
    float x = g1[b * D + t];
    float y = g2[b * D + t];
    __shared__ float sx[2], sy[2], sp[2];
    float xs = wave_reduce_sum(x * x);
    float ys = wave_reduce_sum(y * y);
    if (lane == 0) { sx[w] = xs; sy[w] = ys; }
    __syncthreads();
    float ix = 1.0f / fmaxf(sqrtf(sx[0] + sx[1]), EPS);
    float iy = 1.0f / fmaxf(sqrtf(sy[0] + sy[1]), EPS);
    float qv = x * ix;
    float kv = y * iy;
    qnb[b * D + t] = f2bf(qv);
    float p = wave_reduce_sum(qv * kv);
    if (lane == 0) sp[w] = p;
    __syncthreads();
    if (t == 0) {
        float pos = (sp[0] + sp[1]) * TEMP_INV;
        out_pos[b] = pos;
        ws_pos[b]  = pos;
    }
}

// --- K2: l2-normalize queue rows -> bf16 qb -------------------------------
// one wave per row (lane holds 2 elems), 4 rows per 256-thread block
__global__ void k_qnorm(const float* __restrict__ queue,
                        unsigned short* __restrict__ qb) {
    int wv = threadIdx.x >> 6;
    int lane = threadIdx.x & 63;
    int row = blockIdx.x * 4 + wv;
    const float2* p = (const float2*)(queue + (size_t)row * D);
    float2 v = p[lane];
    float s = wave_reduce_sum(v.x * v.x + v.y * v.y);
    float inv = 1.0f / fmaxf(sqrtf(s), EPS);
    unsigned int lo = f2bf(v.x * inv);
    unsigned int hi = f2bf(v.y * inv);
    *(unsigned int*)(qb + (size_t)row * D + lane * 2) = lo | (hi << 16);
}

// --- K3: MFMA GEMM + fused partial-LSE ------------------------------------
// C[b][j] = (qn[b] . qb[j]) * 5 ; 128x128 tile, 4 waves (2x2), 64x64 per wave
__global__ __launch_bounds__(256) void k_gemm_mfma(const unsigned short* __restrict__ qnb,
                                                   const unsigned short* __restrict__ qb,
                                                   float* __restrict__ neg,
                                                   float* __restrict__ pm,
                                                   float* __restrict__ ps) {
    __shared__ unsigned short As[128][136];   // +8 pad: 272B row stride
    __shared__ unsigned short Bs[128][136];
    const int t  = threadIdx.x;
    const int bx = blockIdx.x;     // 0..511 over Q
    const int by = blockIdx.y;     // 0..7   over B
    const int R0 = by * 128, C0 = bx * 128;

    // stage A (q rows) and B (queue rows), both K-major bf16
    {
        int r  = t >> 4;             // 0..15
        int c8 = (t & 15) * 8;       // bf16 col, 16B chunks
        #pragma unroll
        for (int pass = 0; pass < 8; ++pass) {
            int rr = r + pass * 16;
            uint4 va = *(const uint4*)(qnb + (size_t)(R0 + rr) * D + c8);
            uint4 vb = *(const uint4*)(qb  + (size_t)(C0 + rr) * D + c8);
            *(uint4*)&As[rr][c8] = va;
            *(uint4*)&Bs[rr][c8] = vb;
        }
    }
    __syncthreads();

    const int wid = t >> 6, lane = t & 63;
    const int wr = wid >> 1, wc = wid & 1;    // 2x2 wave grid
    const int lg = lane >> 4;                 // 0..3
    const int lc = lane & 15;

    f32x4 zero = {0.f, 0.f, 0.f, 0.f};
    f32x4 acc[4][4];
    #pragma unroll
    for (int m = 0; m < 4; ++m)
        #pragma unroll
        for (int n = 0; n < 4; ++n) acc[m][n] = zero;

    #pragma unroll
    for (int kk = 0; kk < D; kk += 32) {
        int ko = kk + lg * 8;
        bf16x8 a[4], b[4];
        #pragma unroll
        for (int m = 0; m < 4; ++m)
            a[m] = *(const bf16x8*)&As[wr * 64 + m * 16 + lc][ko];
        #pragma unroll
        for (int n = 0; n < 4; ++n)
            b[n] = *(const bf16x8*)&Bs[wc * 64 + n * 16 + lc][ko];
        #pragma unroll
        for (int m = 0; m < 4; ++m)
            #pragma unroll
            for (int n = 0; n < 4; ++n)
                acc[m][n] = __builtin_amdgcn_mfma_f32_16x16x32_bf16(a[m], b[n], acc[m][n], 0, 0, 0);
    }

    // epilogue: scale, store, fused partial-LSE per row over this wave's 64 cols
    const int colBase = C0 + wc * 64;
    const int p = bx * 2 + wc;                // partial slot
    #pragma unroll
    for (int m = 0; m < 4; ++m) {
        #pragma unroll
        for (int reg = 0; reg < 4; ++reg) {
            int gr = R0 + wr * 64 + m * 16 + lg * 4 + reg;
            float v[4];
            #pragma unroll
            for (int n = 0; n < 4; ++n) {
                v[n] = acc[m][n][reg] * TEMP_INV;
                neg[(size_t)gr * Q + colBase + n * 16 + lc] = v[n];
            }
            // per-row max over this wave's 64 cols (4 frags x 16 lanes)
            float mx = fmaxf(fmaxf(v[0], v[1]), fmaxf(v[2], v[3]));
            #pragma unroll
            for (int off = 1; off < 16; off <<= 1)
                mx = fmaxf(mx, __shfl_xor(mx, off));
            float se = __expf(v[0] - mx) + __expf(v[1] - mx) +
                       __expf(v[2] - mx) + __expf(v[3] - mx);
            #pragma unroll
            for (int off = 1; off < 16; off <<= 1)
                se += __shfl_xor(se, off);
            if (lc == 0) {
                pm[(size_t)gr * NPART + p] = mx;
                ps[(size_t)gr * NPART + p] = se;
            }
        }
    }
}

// --- K4: reduce 1024 partials per row + pos -> loss_b ---------------------
__global__ __launch_bounds__(256) void k_reduce_lse(const float* __restrict__ pm,
                                                    const float* __restrict__ ps,
                                                    const float* __restrict__ ws_pos,
                                                    float* __restrict__ loss_b) {
    int r = blockIdx.x;
    const float* rm = pm + (size_t)r * NPART;
    const float* rs = ps + (size_t)r * NPART;
    float m = -3.4e38f, s = 0.0f;
    for (int i = threadIdx.x; i < NPART; i += 256) {
        float m2 = rm[i], s2 = rs[i];
        float M = fmaxf(m, m2);
        s = s * __expf(m - M) + s2 * __expf(m2 - M);
        m = M;
    }
    #pragma unroll
    for (int off = 32; off > 0; off >>= 1) {
        float m2 = __shfl_xor(m, off);
        float s2 = __shfl_xor(s, off);
        float M = fmaxf(m, m2);
        s = s * __expf(m - M) + s2 * __expf(m2 - M);
        m = M;
    }
    __shared__ float sm[4], ss[4];
    int w = threadIdx.x >> 6, lane = threadIdx.x & 63;
    if (lane == 0) { sm[w] = m; ss[w] = s; }
    __syncthreads();
    if (threadIdx.x == 0) {
        m = sm[0]; s = ss[0];
        #pragma unroll
        for (int i = 1; i < 4; ++i) {
            float M = fmaxf(m, sm[i]);
            s = s * __expf(m - M) + ss[i] * __expf(sm[i] - M);
            m = M;
        }
        float pos = ws_pos[r];
        float M = fmaxf(m, pos);
        s = s * __expf(m - M) + __expf(pos - M);
        loss_b[r] = (M + logf(s)) - pos;
    }
}

// --- K5: mean of loss_b -> out[0] -----------------------------------------
__global__ void k_loss_mean(const float* __restrict__ loss_b, float* __restrict__ out) {
    float s = 0.0f;
    for (int i = threadIdx.x; i < B; i += 256) s += loss_b[i];
    s = wave_reduce_sum(s);
    __shared__ float sw[4];
    int w = threadIdx.x >> 6, lane = threadIdx.x & 63;
    if (lane == 0) sw[w] = s;
    __syncthreads();
    if (threadIdx.x == 0) out[0] = (sw[0] + sw[1] + sw[2] + sw[3]) / (float)B;
}

extern "C" void kernel_launch(void* const* d_in, const int* in_sizes, int n_in,
                              void* d_out, int out_size, void* d_ws, size_t ws_size,
                              hipStream_t stream) {
    const float* g1    = (const float*)d_in[0];
    const float* g2    = (const float*)d_in[1];
    const float* queue = (const float*)d_in[2];
    float* out = (float*)d_out;

    float* out_pos = out + 1;          // pos_sim [B]
    float* neg     = out + 1 + B;      // neg_sim [B][Q]

    // ws layout: qnb bf16[B*D] | qb bf16[Q*D] | pm f32[B*NPART] | ps f32[B*NPART]
    //            | ws_pos f32[B] | loss_b f32[B]
    unsigned short* qnb = (unsigned short*)d_ws;
    unsigned short* qb  = qnb + (size_t)B * D;
    float* pm     = (float*)(qb + (size_t)Q * D);
    float* ps     = pm + (size_t)B * NPART;
    float* ws_pos = ps + (size_t)B * NPART;
    float* loss_b = ws_pos + B;

    k_norm_pos<<<B, 128, 0, stream>>>(g1, g2, qnb, out_pos, ws_pos);
    k_qnorm<<<Q / 4, 256, 0, stream>>>(queue, qb);
    dim3 g3(Q / 128, B / 128);
    k_gemm_mfma<<<g3, 256, 0, stream>>>(qnb, qb, neg, pm, ps);
    k_reduce_lse<<<B, 256, 0, stream>>>(pm, ps, ws_pos, loss_b);
    k_loss_mean<<<1, 256, 0, stream>>>(loss_b, out);
}

// Round 3
// 102.880 us; speedup vs baseline: 3.8817x; 1.1765x over previous
//
#include <hip/hip_runtime.h>
#include <math.h>

constexpr int B = 1024;
constexpr int D = 128;
constexpr int Q = 65536;
constexpr int NPART = 1024;      // partial-sumexp slots per row (512 col-blocks x 2 wave-cols)
#define TEMP_INV 5.0f
#define EPS 1e-12f

typedef __bf16 bf16x8 __attribute__((ext_vector_type(8)));
typedef float  f32x4  __attribute__((ext_vector_type(4)));

__device__ __forceinline__ float wave_reduce_sum(float v) {
    #pragma unroll
    for (int off = 32; off > 0; off >>= 1) v += __shfl_xor(v, off);
    return v;
}

__device__ __forceinline__ unsigned short f2bf(float x) {
    unsigned int u = __float_as_uint(x);
    unsigned int r = (u + 0x7FFFu + ((u >> 16) & 1u)) >> 16;   // RNE
    return (unsigned short)r;
}

// --- K1: normalize g1,g2 rows; qn (bf16) to ws; pos_sim to out and ws ------
__global__ void k_norm_pos(const float* __restrict__ g1,
                           const float* __restrict__ g2,
                           unsigned short* __restrict__ qnb,
                           float* __restrict__ out_pos,
                           float* __restrict__ ws_pos) {
    int b = blockIdx.x;
    int t = threadIdx.x;           // 0..127
    int w = t >> 6, lane = t & 63;
    float x = g1[b * D + t];
    float y = g2[b * D + t];
    __shared__ float sx[2], sy[2], sp[2];
    float xs = wave_reduce_sum(x * x);
    float ys = wave_reduce_sum(y * y);
    if (lane == 0) { sx[w] = xs; sy[w] = ys; }
    __syncthreads();
    float ix = 1.0f / fmaxf(sqrtf(sx[0] + sx[1]), EPS);
    float iy = 1.0f / fmaxf(sqrtf(sy[0] + sy[1]), EPS);
    float qv = x * ix;
    float kv = y * iy;
    qnb[b * D + t] = f2bf(qv);
    float p = wave_reduce_sum(qv * kv);
    if (lane == 0) sp[w] = p;
    __syncthreads();
    if (t == 0) {
        float pos = (sp[0] + sp[1]) * TEMP_INV;
        out_pos[b] = pos;
        ws_pos[b]  = pos;
    }
}

// --- K2: l2-normalize queue rows -> bf16 qb (float4 loads, 2 rows/wave) ----
__global__ void k_qnorm(const float* __restrict__ queue,
                        unsigned short* __restrict__ qb) {
    int half = threadIdx.x >> 5;        // 0..7
    int l    = threadIdx.x & 31;
    int row  = blockIdx.x * 8 + half;
    float4 v = ((const float4*)(queue + (size_t)row * D))[l];
    float ss = v.x * v.x + v.y * v.y + v.z * v.z + v.w * v.w;
    #pragma unroll
    for (int off = 16; off > 0; off >>= 1) ss += __shfl_xor(ss, off);
    float inv = 1.0f / fmaxf(sqrtf(ss), EPS);
    uint2 o;
    o.x = (unsigned int)f2bf(v.x * inv) | ((unsigned int)f2bf(v.y * inv) << 16);
    o.y = (unsigned int)f2bf(v.z * inv) | ((unsigned int)f2bf(v.w * inv) << 16);
    ((uint2*)(qb + (size_t)row * D))[l] = o;
}

// --- K3: MFMA GEMM + fused fixed-ref partial sumexp -----------------------
// C[b][j] = (qn[b].qb[j])*5 ; 128x128 tile, 4 waves (2x2), 64x64 per wave
// K staged in two 64-wide steps (LDS 36.9KB -> 3 blocks/CU)
__global__ __launch_bounds__(256, 3) void k_gemm_mfma(const unsigned short* __restrict__ qnb,
                                                      const unsigned short* __restrict__ qb,
                                                      float* __restrict__ neg,
                                                      float* __restrict__ psum) {
    __shared__ unsigned short As[128][72];   // +8 pad: 144B row stride (2-way banks only)
    __shared__ unsigned short Bs[128][72];
    const int t  = threadIdx.x;
    const int bx = blockIdx.x;     // 0..511 over Q
    const int by = blockIdx.y;     // 0..7   over B
    const int R0 = by * 128, C0 = bx * 128;
    const int wid = t >> 6, lane = t & 63;
    const int wr = wid >> 1, wc = wid & 1;
    const int lg = lane >> 4, lc = lane & 15;

    f32x4 acc[4][4];
    #pragma unroll
    for (int m = 0; m < 4; ++m)
        #pragma unroll
        for (int n = 0; n < 4; ++n)
            #pragma unroll
            for (int r = 0; r < 4; ++r) acc[m][n][r] = 0.0f;

    #pragma unroll
    for (int s = 0; s < 2; ++s) {
        if (s) __syncthreads();
        const int ks = s * 64;
        #pragma unroll
        for (int p = 0; p < 4; ++p) {
            int c   = t + 256 * p;
            int row = c >> 3;          // 0..127
            int off = (c & 7) * 8;     // bf16 units, 0..56
            uint4 va = *(const uint4*)(qnb + (size_t)(R0 + row) * D + ks + off);
            uint4 vb = *(const uint4*)(qb  + (size_t)(C0 + row) * D + ks + off);
            *(uint4*)&As[row][off] = va;
            *(uint4*)&Bs[row][off] = vb;
        }
        __syncthreads();
        #pragma unroll
        for (int kk = 0; kk < 64; kk += 32) {
            int ko = kk + lg * 8;
            bf16x8 a[4], b[4];
            #pragma unroll
            for (int m = 0; m < 4; ++m)
                a[m] = *(const bf16x8*)&As[wr * 64 + m * 16 + lc][ko];
            #pragma unroll
            for (int n = 0; n < 4; ++n)
                b[n] = *(const bf16x8*)&Bs[wc * 64 + n * 16 + lc][ko];
            #pragma unroll
            for (int m = 0; m < 4; ++m)
                #pragma unroll
                for (int n = 0; n < 4; ++n)
                    acc[m][n] = __builtin_amdgcn_mfma_f32_16x16x32_bf16(a[m], b[n], acc[m][n], 0, 0, 0);
        }
    }

    // ---- epilogue: per 32-row slice: LDS-stage (reusing Bs), fused sumexp,
    //      coalesced float4 stores. Fixed LSE reference M=5 (logits in [-5,5]).
    float* Cs = (float*)&Bs[0][0];     // [32][132] f32 = 16896B <= sizeof(Bs)
    const int slot = bx * 2 + wc;
    #pragma unroll
    for (int m = 0; m < 4; ++m) {
        __syncthreads();               // prev slice's reads (or MFMA Bs reads) done
        #pragma unroll
        for (int reg = 0; reg < 4; ++reg) {
            float v0 = acc[m][0][reg] * TEMP_INV;
            float v1 = acc[m][1][reg] * TEMP_INV;
            float v2 = acc[m][2][reg] * TEMP_INV;
            float v3 = acc[m][3][reg] * TEMP_INV;
            int cr = (wr * 16 + lg * 4 + reg) * 132 + wc * 64 + lc;
            Cs[cr +  0] = v0;
            Cs[cr + 16] = v1;
            Cs[cr + 32] = v2;
            Cs[cr + 48] = v3;
            float e = __expf(v0 - 5.0f) + __expf(v1 - 5.0f) +
                      __expf(v2 - 5.0f) + __expf(v3 - 5.0f);
            #pragma unroll
            for (int off = 1; off < 16; off <<= 1) e += __shfl_xor(e, off);
            if (lc == 0) {
                int gr = R0 + wr * 64 + m * 16 + lg * 4 + reg;
                psum[(size_t)gr * NPART + slot] = e;
            }
        }
        __syncthreads();
        #pragma unroll
        for (int p = 0; p < 4; ++p) {
            int f  = t + 256 * p;
            int lr = f >> 5, c4 = f & 31;
            int gr = R0 + (lr >> 4) * 64 + m * 16 + (lr & 15);
            float4 o = *(const float4*)&Cs[lr * 132 + c4 * 4];
            *(float4*)(neg + (size_t)gr * Q + C0 + c4 * 4) = o;
        }
    }
}

// --- K4: reduce 1024 partial sums per row + pos -> loss_b -----------------
__global__ __launch_bounds__(256) void k_reduce_lse(const float* __restrict__ psum,
                                                    const float* __restrict__ ws_pos,
                                                    float* __restrict__ loss_b) {
    int r = blockIdx.x;
    const float4* pr = (const float4*)(psum + (size_t)r * NPART);
    float4 v = pr[threadIdx.x];        // 256 threads x float4 = 1024 slots
    float s = v.x + v.y + v.z + v.w;
    s = wave_reduce_sum(s);
    __shared__ float sw[4];
    int w = threadIdx.x >> 6, lane = threadIdx.x & 63;
    if (lane == 0) sw[w] = s;
    __syncthreads();
    if (threadIdx.x == 0) {
        float S = sw[0] + sw[1] + sw[2] + sw[3];
        float pos = ws_pos[r];
        S += __expf(pos - 5.0f);
        loss_b[r] = (logf(S) + 5.0f) - pos;   // lse - pos
    }
}

// --- K5: mean of loss_b -> out[0] -----------------------------------------
__global__ void k_loss_mean(const float* __restrict__ loss_b, float* __restrict__ out) {
    float s = 0.0f;
    for (int i = threadIdx.x; i < B; i += 256) s += loss_b[i];
    s = wave_reduce_sum(s);
    __shared__ float sw[4];
    int w = threadIdx.x >> 6, lane = threadIdx.x & 63;
    if (lane == 0) sw[w] = s;
    __syncthreads();
    if (threadIdx.x == 0) out[0] = (sw[0] + sw[1] + sw[2] + sw[3]) / (float)B;
}

extern "C" void kernel_launch(void* const* d_in, const int* in_sizes, int n_in,
                              void* d_out, int out_size, void* d_ws, size_t ws_size,
                              hipStream_t stream) {
    const float* g1    = (const float*)d_in[0];
    const float* g2    = (const float*)d_in[1];
    const float* queue = (const float*)d_in[2];
    float* out = (float*)d_out;

    float* out_pos = out + 1;          // pos_sim [B]
    float* neg     = out + 1 + B;      // neg_sim [B][Q]

    // ws layout: qnb bf16[B*D] | qb bf16[Q*D] | psum f32[B*NPART]
    //            | ws_pos f32[B] | loss_b f32[B]
    unsigned short* qnb = (unsigned short*)d_ws;
    unsigned short* qb  = qnb + (size_t)B * D;
    float* psum   = (float*)(qb + (size_t)Q * D);
    float* ws_pos = psum + (size_t)B * NPART;
    float* loss_b = ws_pos + B;

    k_norm_pos<<<B, 128, 0, stream>>>(g1, g2, qnb, out_pos, ws_pos);
    k_qnorm<<<Q / 8, 256, 0, stream>>>(queue, qb);
    dim3 g3(Q / 128, B / 128);
    k_gemm_mfma<<<g3, 256, 0, stream>>>(qnb, qb, neg, psum);
    k_reduce_lse<<<B, 256, 0, stream>>>(psum, ws_pos, loss_b);
    k_loss_mean<<<1, 256, 0, stream>>>(loss_b, out);
}